// Round 15
// baseline (2185.356 us; speedup 1.0000x reference)
//
#include <hip/hip_runtime.h>

using u16 = unsigned short;
using u32 = unsigned int;
using u64 = unsigned long long;
using f32x4 = __attribute__((ext_vector_type(4))) float;
using s16x8 = __attribute__((ext_vector_type(8))) short;
using u32x4 = __attribute__((ext_vector_type(4))) unsigned int;

// ---------- helpers ----------
__device__ __forceinline__ u16 f2b(float f) {
  union { float f; u32 u; } v; v.f = f;
  u32 r = v.u + 0x7fffu + ((v.u >> 16) & 1u);
  return (u16)(r >> 16);
}
__device__ __forceinline__ float b2f(u16 h) {
  union { u32 u; float f; } v; v.u = ((u32)h) << 16; return v.f;
}
__device__ __forceinline__ void gl_lds16(const u16* g, u16* l) {
  __builtin_amdgcn_global_load_lds(
      (const __attribute__((address_space(1))) void*)g,
      (__attribute__((address_space(3))) void*)l, 16, 0, 0);
}
__device__ __forceinline__ float fsigm(float x) {
  return 1.f / (1.f + __expf(-x));
}
__device__ __forceinline__ float ftanh(float x) {
  float ax = fabsf(x);
  float e2 = __expf(2.f * ax);
  float th = 1.f - 2.f / (e2 + 1.f);
  return copysignf(th, x);
}

// ---------- tiny prep kernels ----------
__global__ void k_cast(const float* __restrict__ s, u16* __restrict__ d, int n) {
  int i = blockIdx.x * 256 + threadIdx.x;
  if (i < n) d[i] = f2b(s[i]);
}

// INTERLEAVED mu|sg weight concat+cast: dst[l][r][k], r = 2p + s (s=0:mu, s=1:sg)
__global__ void k_musgw(const float* __restrict__ muw, const float* __restrict__ sgw,
                        u16* __restrict__ dst, int n) {
  int i = blockIdx.x * 256 + threadIdx.x;
  if (i >= n) return;
  int l = i / (384 * 1216);
  int r = (i / 1216) % 384;
  int k = i % 1216;
  int p = r >> 1;
  const float* s = (r & 1) ? (sgw + ((long)l * 192 + p) * 1216 + k)
                           : (muw + ((long)l * 192 + p) * 1216 + k);
  dst[i] = f2b(*s);
}

// interleaved bias
__global__ void k_catb(const float* __restrict__ mub, const float* __restrict__ sgb,
                       float* __restrict__ catb) {
  int i = blockIdx.x * 256 + threadIdx.x;
  if (i >= 1536) return;
  int l = i / 384, r = i % 384;
  int p = r >> 1;
  catb[i] = (r & 1) ? sgb[l * 192 + p] : mub[l * 192 + p];
}

// conv_w (NF,C,C,2) -> Aw[l][o][tap*512+i] bf16
__global__ void k_convw(const float* __restrict__ cw, u16* __restrict__ Aw, int n) {
  int i = blockIdx.x * 256 + threadIdx.x;
  if (i >= n) return;
  int l = i >> 19;
  int r1 = i & 524287;
  int o = r1 >> 10;
  int r2 = r1 & 1023;
  int tap = r2 >> 9;
  int ii = r2 & 511;
  Aw[i] = f2b(cw[(((long)(l * 512 + o)) * 512 + ii) * 2 + tap]);
}

// whh (3H,H) f32 -> fragment-ordered bf16 blob for k_gru (32 j-owners x 4 waves)
__global__ void k_gruw(const float* __restrict__ whh, u16* __restrict__ blob) {
  int i = blockIdx.x * 256 + threadIdx.x;   // 393216 threads
  int lane = i & 63;
  int c = (i >> 6) & 15;
  int g = (i >> 10) % 3;
  int wwv = i / 3072;
  int wv = wwv & 3, wg = wwv >> 2;
  int jbw = wv & 1, kw = wv >> 1;
  int j = wg * 32 + jbw * 16 + (lane & 15);
  int k = kw * 512 + c * 32 + (lane >> 4) * 8;
  const float* src = whh + ((long)(g * 1024 + j)) * 1024 + k;
  u16* dst = blob + (long)i * 8;
#pragma unroll
  for (int v = 0; v < 8; ++v) dst[v] = f2b(src[v]);
}

// x_enc (B,C,L) f32 -> xT2 (t*32+b, C) bf16  (t-major rows for fused xw GEMM)
__global__ __launch_bounds__(256) void k_txe(const float* __restrict__ x, u16* __restrict__ xT) {
  __shared__ float tile[32][33];
  int l0 = blockIdx.x * 32, c0 = blockIdx.y * 32, b = blockIdx.z;
  int tid = threadIdx.x;
  for (int q = 0; q < 4; ++q) {
    int idx = tid + q * 256;
    int r = idx >> 5, cc = idx & 31;
    int l = l0 + cc;
    tile[r][cc] = (l < 336) ? x[((long)b * 512 + c0 + r) * 336 + l] : 0.f;
  }
  __syncthreads();
  for (int q = 0; q < 4; ++q) {
    int idx = tid + q * 256;
    int r = idx >> 5, cc = idx & 31;
    int l = l0 + r;
    if (l < 336) xT[((long)l * 32 + b) * 512 + c0 + cc] = f2b(tile[cc][r]);
  }
}

// hbuf (B,C,1216) f32 -> hbT (B,1216,C) bf16  — vectorized (float4 in, ushort4 out)
__global__ __launch_bounds__(256) void k_hbt(const float* __restrict__ hbuf, u16* __restrict__ hbT) {
  __shared__ float tile[32][65];
  int t0 = blockIdx.x * 64, c0 = blockIdx.y * 32, b = blockIdx.z;
  int tid = threadIdx.x;
#pragma unroll
  for (int q = 0; q < 2; ++q) {
    int idx = tid + q * 256;
    int r = idx >> 4, col = (idx & 15) * 4;
    *(float4*)&tile[r][col] =
        *(const float4*)&hbuf[((long)b * 512 + c0 + r) * 1216 + t0 + col];
  }
  __syncthreads();
#pragma unroll
  for (int q = 0; q < 2; ++q) {
    int idx = tid + q * 256;
    int t = idx >> 3, cg = (idx & 7) * 4;
    ushort4 o;
    o.x = f2b(tile[cg + 0][t]);
    o.y = f2b(tile[cg + 1][t]);
    o.z = f2b(tile[cg + 2][t]);
    o.w = f2b(tile[cg + 3][t]);
    *(ushort4*)&hbT[((long)b * 1216 + t0 + t) * 512 + c0 + cg] = o;
  }
}

// sample (B,C,P) f32 -> out (B,P,C) f32
__global__ __launch_bounds__(256) void k_out(const float* __restrict__ smp, float* __restrict__ out) {
  __shared__ float tile[32][33];
  int p0 = blockIdx.x * 32, c0 = blockIdx.y * 32, b = blockIdx.z;
  int tid = threadIdx.x;
  for (int q = 0; q < 4; ++q) {
    int idx = tid + q * 256;
    int r = idx >> 5, cc = idx & 31;
    tile[r][cc] = smp[((long)b * 512 + c0 + r) * 192 + p0 + cc];
  }
  __syncthreads();
  for (int q = 0; q < 4; ++q) {
    int idx = tid + q * 256;
    int r = idx >> 5, cc = idx & 31;
    out[((long)b * 192 + p0 + r) * 512 + c0 + cc] = tile[cc][r];
  }
}

// ---------- MFMA GEMM: C[M,N] = A(M,K) @ Bt(N,K)^T ----------
// MODE 2: conv epilogue ; MODE 5: fused mu|sg sample update
// TPZ>0: XCD-locality swizzle (T1): bid = ((zhi*TPZ + tile)<<3)|xcd, z = zhi*8+xcd
template<int MODE, int TPZ = 0, int NX = 1>
__global__ __launch_bounds__(256, 2)
void gemm_bt(const u16* __restrict__ A, const u16* __restrict__ Bt,
             void* __restrict__ Cv, const float* __restrict__ bias,
             int M, int N, int K, int lda, int ldb, int ldc,
             long sA, long sB, long sC,
             int arowmax, int browmax, int NT,
             float* __restrict__ hbufp, long sH,
             float* __restrict__ sampleP, long sS)
{
  __shared__ u16 As[128 * 64];
  __shared__ u16 Bs[128 * 64];
  const int tid = threadIdx.x;
  const int lane = tid & 63;
  const int wv = tid >> 6;
  int bx, by, bz;
  if (TPZ > 0) {
    int bid = (int)blockIdx.x;
    int xcd = bid & 7, idx = bid >> 3;
    int zhi = idx / TPZ, r = idx - zhi * TPZ;
    bz = zhi * 8 + xcd;
    by = r / NX;
    bx = r - by * NX;
  } else {
    bx = (int)blockIdx.x; by = (int)blockIdx.y; bz = (int)blockIdx.z;
  }
  const int z = bz;
  const u16* Ab = A + (long)z * sA;
  const u16* Bb = Bt + (long)z * sB;
  const int m0 = by * 128, n0 = bx * 128;
  const int wm = (wv >> 1) * 64, wn = (wv & 1) * 64;

  f32x4 acc[4][4] = {};

  for (int kt = 0; kt < K; kt += 64) {
#pragma unroll
    for (int s = 0; s < 4; ++s) {
      int row = (wv * 4 + s) * 8 + (lane >> 3);
      int ck = (lane & 7) ^ (row & 7);       // source chunk pre-swizzle (T2)
      int ra = m0 + row; if (ra > arowmax) ra = arowmax;
      gl_lds16(Ab + (long)ra * lda + (kt + ck * 8), As + (wv * 4 + s) * 512);
      int rb = n0 + row; if (rb > browmax) rb = browmax;
      gl_lds16(Bb + (long)rb * ldb + (kt + ck * 8), Bs + (wv * 4 + s) * 512);
    }
    __syncthreads();
#pragma unroll
    for (int kk = 0; kk < 64; kk += 32) {
      s16x8 af[4], bfr[4];
#pragma unroll
      for (int i = 0; i < 4; ++i) {
        int rowa = wm + i * 16 + (lane & 15);
        int offa = (rowa * 128 + (kk + 8 * (lane >> 4)) * 2) ^ ((rowa & 7) << 4);
        af[i] = *(const s16x8*)((const char*)As + offa);
        int rowb = wn + i * 16 + (lane & 15);
        int offb = (rowb * 128 + (kk + 8 * (lane >> 4)) * 2) ^ ((rowb & 7) << 4);
        bfr[i] = *(const s16x8*)((const char*)Bs + offb);
      }
#pragma unroll
      for (int i = 0; i < 4; ++i)
#pragma unroll
        for (int j = 0; j < 4; ++j)
          acc[i][j] = __builtin_amdgcn_mfma_f32_16x16x32_bf16(af[i], bfr[j], acc[i][j], 0, 0, 0);
    }
    __syncthreads();
  }

  u16* Cb16 = (u16*)Cv;
#pragma unroll
  for (int i = 0; i < 4; ++i) {
#pragma unroll
    for (int j = 0; j < 4; ++j) {
      const int mb = m0 + wm + i * 16 + 4 * (lane >> 4);
      const int n = n0 + wn + j * 16 + (lane & 15);
      if (n >= NT) continue;
      f32x4 v = acc[i][j];
      if (MODE == 2) {
        u16* Cp = Cb16 + (long)z * sC;
        float* hb = hbufp + (long)z * sH;
#pragma unroll
        for (int r = 0; r < 4; ++r) {
          int m = mb + r;
          float x = v[r] + bias[m];
          x = fmaxf(x, 0.0f);
          u16 hx = f2b(x);
          Cp[(long)m * ldc + (n + 1)] = hx;
          if (n + 1 < 1024) hb[(long)m * 1216 + (n + 1)] += 0.1f * x;
          if (n == 0) { Cp[(long)m * ldc] = hx; hb[(long)m * 1216] += 0.1f * x; }
        }
      } else { // MODE 5
        float bn = bias[n];
        float* hb = hbufp + (long)z * sH;
        float* smp = sampleP + (long)z * sS;
        const int p = n >> 1;
#pragma unroll
        for (int r = 0; r < 4; ++r) {
          float val = v[r] + bn;              // even lane: mu ; odd lane: sg
          float other = __shfl_xor(val, 1);   // partner value
          if ((lane & 1) == 0) {
            int m = mb + r;
            long si = (long)m * 192 + p;
            float snew = val + __expf(0.5f * other) * smp[si] * 0.1f;
            smp[si] = snew;
            hb[(long)m * 1216 + 1024 + p] += 0.1f * snew;
          }
        }
      }
    }
  }
}

// ---------- FUSED GRU scan + xw producer GEMM ----------
// Grid = 64 + 84*24 = 2080 WGs.
//  WGs 0-63: two parallel 32-WG GRU teams (r13 protocol, wide-sc1 h transport).
//  WGs 64+ : xw GEMM tiles (A=xT2 t-major, B=wih16), by = tile/24 ascending so
//            early-t tiles dispatch first. Producer: plain C stores -> drain ->
//            threadfence (L2 writeback) -> done[by]++ (agent atomic).
//  Consumer wave0 poll: lanes 0-31 team flags, lane 32 done[t>>2] >= 24.
//  GRU first touches xw lines only after watermark -> no stale-cache hazard.
__global__ __launch_bounds__(256, 1)
void k_gru(const u16* __restrict__ xT2, const u16* __restrict__ wih16,
           const float* __restrict__ bih, u16* __restrict__ xw, u32* __restrict__ done,
           const u16* __restrict__ wblob, const float* __restrict__ bhh,
           u64* __restrict__ hfA, u64* __restrict__ hfB,
           float* __restrict__ hTt, float* __restrict__ hTn, u32* __restrict__ flags)
{
  __shared__ __align__(16) char smem[32768];
  const int tid = threadIdx.x;
  const int lane = tid & 63;
  const int wv = tid >> 6;

  if (blockIdx.x >= 64) {
    // ================= xw GEMM producer role =================
    u16* As = (u16*)smem;
    u16* Bs = As + 8192;
    const int bid2 = (int)blockIdx.x - 64;
    const int by = bid2 / 24, bx = bid2 - by * 24;
    const int m0 = by * 128, n0 = bx * 128;
    const int wm = (wv >> 1) * 64, wn = (wv & 1) * 64;
    f32x4 acc[4][4] = {};
    for (int kt = 0; kt < 512; kt += 64) {
#pragma unroll
      for (int s = 0; s < 4; ++s) {
        int row = (wv * 4 + s) * 8 + (lane >> 3);
        int ck = (lane & 7) ^ (row & 7);
        gl_lds16(xT2 + (long)(m0 + row) * 512 + (kt + ck * 8), As + (wv * 4 + s) * 512);
        gl_lds16(wih16 + (long)(n0 + row) * 512 + (kt + ck * 8), Bs + (wv * 4 + s) * 512);
      }
      __syncthreads();
#pragma unroll
      for (int kk = 0; kk < 64; kk += 32) {
        s16x8 af[4], bfr[4];
#pragma unroll
        for (int i = 0; i < 4; ++i) {
          int rowa = wm + i * 16 + (lane & 15);
          int offa = (rowa * 128 + (kk + 8 * (lane >> 4)) * 2) ^ ((rowa & 7) << 4);
          af[i] = *(const s16x8*)((const char*)As + offa);
          int rowb = wn + i * 16 + (lane & 15);
          int offb = (rowb * 128 + (kk + 8 * (lane >> 4)) * 2) ^ ((rowb & 7) << 4);
          bfr[i] = *(const s16x8*)((const char*)Bs + offb);
        }
#pragma unroll
        for (int i = 0; i < 4; ++i)
#pragma unroll
          for (int j = 0; j < 4; ++j)
            acc[i][j] = __builtin_amdgcn_mfma_f32_16x16x32_bf16(af[i], bfr[j], acc[i][j], 0, 0, 0);
      }
      __syncthreads();
    }
#pragma unroll
    for (int i = 0; i < 4; ++i) {
#pragma unroll
      for (int j = 0; j < 4; ++j) {
        const int mb = m0 + wm + i * 16 + 4 * (lane >> 4);
        const int n = n0 + wn + j * 16 + (lane & 15);
        float bn = bih[n];
#pragma unroll
        for (int r = 0; r < 4; ++r)
          xw[(long)(mb + r) * 3072 + n] = f2b(acc[i][j][r] + bn);
      }
    }
    asm volatile("s_waitcnt vmcnt(0)" ::: "memory");
    __syncthreads();
    if (tid == 0) {
      __threadfence();   // L2 writeback: xw tile visible at MALL
      __hip_atomic_fetch_add(&done[by], 1u, __ATOMIC_RELAXED, __HIP_MEMORY_SCOPE_AGENT);
    }
    return;
  }

  // ================= GRU role (r13 protocol) =================
  float (*part)[32][32] = (float(*)[32][32])smem;   // [6][32][32]
  const int q = (int)(blockIdx.x >> 5);   // team = batch half
  const int tw = (int)(blockIdx.x & 31);  // j-range owner within team
  const int jbw = wv & 1, kw = wv >> 1;
  u32* __restrict__ myflags = flags + q * 1024;

  s16x8 bfr[3][16];
  {
    const u16* wp = wblob + (long)(tw * 4 + wv) * 24576 + lane * 8;
#pragma unroll
    for (int g = 0; g < 3; ++g)
#pragma unroll
      for (int c = 0; c < 16; ++c)
        bfr[g][c] = *(const s16x8*)(wp + (g * 16 + c) * 512);
  }

  const int bq16 = tid & 15, jg = (tid >> 4) & 7;
  const int j0 = tw * 32 + jg * 4;
  const int bb = q * 16 + bq16;
  float b3[3][4];
#pragma unroll
  for (int g = 0; g < 3; ++g)
#pragma unroll
    for (int jj = 0; jj < 4; ++jj) b3[g][jj] = bhh[g * 1024 + j0 + jj];
  ushort4 hold = make_ushort4(0, 0, 0, 0);

  const long hoff64 = (long)(tw * 2 + q) * 128 + ((long)(jg >> 1) * 16 + bq16) * 2;
  const int myflag = tw * 32;

  for (int t = 0; t < 336; ++t) {
    const u64* __restrict__ hr = (t & 1) ? hfB : hfA;
    u64* __restrict__ hw = (t & 1) ? hfA : hfB;

    // poll: team flags (lanes 0-31, t>0) + xw watermark (lane 32)
    if (wv == 0) {
      int spins = 0;
      while (true) {
        bool ok;
        if (lane < 32)
          ok = (t == 0) || (__hip_atomic_load(&myflags[lane * 32], __ATOMIC_RELAXED,
                                              __HIP_MEMORY_SCOPE_AGENT) >= (u32)t);
        else if (lane == 32)
          ok = (__hip_atomic_load(&done[t >> 2], __ATOMIC_RELAXED,
                                  __HIP_MEMORY_SCOPE_AGENT) >= 24u);
        else
          ok = true;
        if (__ballot(ok) == ~0ull) break;
        __builtin_amdgcn_s_sleep(1);
        if (++spins > (1 << 22)) break;   // safety
      }
    }
    __syncthreads();     // release waves; WAR guard on part[]
    __builtin_amdgcn_sched_barrier(0);

    // xw slice loads (plain; first touch is after watermark -> fresh from MALL)
    ushort4 xr = {}, xz = {}, xn = {};
    if (tid < 128) {
      const u16* xp = xw + ((long)t * 32 + bb) * 3072 + j0;
      xr = *(const ushort4*)(xp);
      xz = *(const ushort4*)(xp + 1024);
      xn = *(const ushort4*)(xp + 2048);
    }

    // consume h_t (own batch half): 16 x 16B sc1 loads, all in flight, one wait
    u32x4 md[16];
#pragma unroll
    for (int c = 0; c < 16; ++c) {
      const int cg = kw * 16 + c;
      u64 a0 = (u64)(const void*)(hr + ((long)(cg * 2 + q) * 64 + lane) * 2);
      asm volatile("global_load_dwordx4 %0, %1, off sc1" : "=v"(md[c]) : "v"(a0) : "memory");
    }
    asm volatile("s_waitcnt vmcnt(0)" ::: "memory");
    __builtin_amdgcn_sched_barrier(0);   // rule #18

    f32x4 acc[3] = {};
#pragma unroll
    for (int c = 0; c < 16; ++c) {
      union { u32x4 d; s16x8 v; } au;
      au.d = md[c];
#pragma unroll
      for (int g = 0; g < 3; ++g)
        acc[g] = __builtin_amdgcn_mfma_f32_16x16x32_bf16(au.v, bfr[g][c], acc[g], 0, 0, 0);
    }
    {
      const int jl = jbw * 16 + (lane & 15);
      const int swz = ((jl & 1) << 4) | ((jl & 6) << 1);
      const int s4 = (lane >> 4) * 4;
#pragma unroll
      for (int g = 0; g < 3; ++g)
        *(f32x4*)&part[kw * 3 + g][jl][(16 * q + s4) ^ swz] = acc[g];
    }
    __syncthreads();

    if (tid < 128) {
      float hnew[4];
#pragma unroll
      for (int jj = 0; jj < 4; ++jj) {
        const int jl = jg * 4 + jj;
        const int swz = ((jl & 1) << 4) | ((jl & 6) << 1);
        const int slot = (16 * q + bq16) ^ swz;
        float s0 = part[0][jl][slot] + part[3][jl][slot] + b3[0][jj];
        float s1 = part[1][jl][slot] + part[4][jl][slot] + b3[1][jj];
        float s2 = part[2][jl][slot] + part[5][jl][slot] + b3[2][jj];
        float xrv = b2f(((const u16*)&xr)[jj]);
        float xzv = b2f(((const u16*)&xz)[jj]);
        float xnv = b2f(((const u16*)&xn)[jj]);
        float rg = fsigm(xrv + s0);
        float zg = fsigm(xzv + s1);
        float ng = ftanh(xnv + rg * s2);
        float holdv = b2f(((const u16*)&hold)[jj]);
        hnew[jj] = (1.f - zg) * ng + zg * holdv;
      }
      ((u16*)&hold)[0] = f2b(hnew[0]);
      ((u16*)&hold)[1] = f2b(hnew[1]);
      ((u16*)&hold)[2] = f2b(hnew[2]);
      ((u16*)&hold)[3] = f2b(hnew[3]);

      {
        union { ushort4 s; u32 d[2]; } hq; hq.s = hold;
        u32 p0 = (u32)__shfl_xor((int)hq.d[0], 16);
        u32 p1 = (u32)__shfl_xor((int)hq.d[1], 16);
        if ((lane & 16) == 0) {
          union { u32 d[4]; u32x4 v; } st;
          st.d[0] = hq.d[0]; st.d[1] = hq.d[1]; st.d[2] = p0; st.d[3] = p1;
          u64 ad = (u64)(void*)(hw + hoff64);
          asm volatile("global_store_dwordx4 %0, %1, off sc1" :: "v"(ad), "v"(st.v) : "memory");
        }
      }
      if (t == 335) {
#pragma unroll
        for (int jj = 0; jj < 4; ++jj) hTt[(j0 + jj) * 32 + bb] = hnew[jj];
        *(float4*)(hTn + bb * 1024 + j0) = make_float4(hnew[0], hnew[1], hnew[2], hnew[3]);
      }
    }
    asm volatile("s_waitcnt vmcnt(0)" ::: "memory");
    __syncthreads();
    if (tid == 0)
      __hip_atomic_store(&myflags[myflag], (u32)(t + 1), __ATOMIC_RELAXED, __HIP_MEMORY_SCOPE_AGENT);
  }
}

// ---------- encoder-head micro GEMMs ----------
__global__ __launch_bounds__(256) void k_encsmall(
    const float* __restrict__ hTt, const float* __restrict__ emw, const float* __restrict__ epw,
    float* __restrict__ Am, float* __restrict__ Asg, float* __restrict__ Sm, float* __restrict__ Ssg)
{
  int q = blockIdx.x * 256 + threadIdx.x;
  int p = q >> 3, bg = q & 7;
  float am[4] = {0.f, 0.f, 0.f, 0.f}, as[4] = {0.f, 0.f, 0.f, 0.f};
  float sm = 0.f, ss = 0.f;
  const float* wmp = emw + (long)p * 1024;
  const float* wsp = epw + (long)p * 1024;
  for (int k = 0; k < 1024; ++k) {
    float a = wmp[k], b = wsp[k];
    f32x4 hv = *(const f32x4*)(hTt + k * 32 + bg * 4);
#pragma unroll
    for (int i = 0; i < 4; ++i) { am[i] += a * hv[i]; as[i] += b * hv[i]; }
    sm += a; ss += b;
  }
#pragma unroll
  for (int i = 0; i < 4; ++i) {
    Am[(bg * 4 + i) * 192 + p] = am[i];
    Asg[(bg * 4 + i) * 192 + p] = as[i];
  }
  if (bg == 0) { Sm[p] = sm; Ssg[p] = ss; }
}

// ---------- build hbuf (enc | sample) + sample ----------
__global__ __launch_bounds__(256) void k_build(
    const float* __restrict__ hTn, const float* __restrict__ fw, const float* __restrict__ fb,
    const float* __restrict__ Am, const float* __restrict__ Asg,
    const float* __restrict__ Sm, const float* __restrict__ Ssg,
    const float* __restrict__ emub, const float* __restrict__ epsb,
    const float* __restrict__ eps, float* __restrict__ hbuf, float* __restrict__ sample)
{
  int c = blockIdx.x, b = blockIdx.y, tid = threadIdx.x;
  float fwc = fw[c], fbc = fb[c];
  long hb0 = ((long)b * 512 + c) * 1216;
  const float* hrow = hTn + b * 1024;
  for (int q = 0; q < 4; ++q) {
    int tt = tid + q * 256;
    hbuf[hb0 + tt] = hrow[tt] * fwc + fbc;
  }
  if (tid < 192) {
    int p = tid;
    float mu_e = fwc * Am[b * 192 + p] + fbc * Sm[p] + emub[p];
    float pse = fwc * Asg[b * 192 + p] + fbc * Ssg[p] + epsb[p];
    float sgv = (pse > 15.f) ? pse : log1pf(__expf(pse));
    long si = ((long)b * 512 + c) * 192 + p;
    float smp = mu_e + __expf(0.5f * sgv) * eps[si];
    sample[si] = smp;
    hbuf[hb0 + 1024 + p] = smp;
  }
}

// ---------- launch ----------
extern "C" void kernel_launch(void* const* d_in, const int* in_sizes, int n_in,
                              void* d_out, int out_size, void* d_ws, size_t ws_size,
                              hipStream_t stream)
{
  const float* x_enc = (const float*)d_in[0];
  const float* eps   = (const float*)d_in[1];
  const float* wih   = (const float*)d_in[2];
  const float* whh   = (const float*)d_in[3];
  const float* bih   = (const float*)d_in[4];
  const float* bhh   = (const float*)d_in[5];
  const float* fw    = (const float*)d_in[6];
  const float* fb    = (const float*)d_in[7];
  const float* emw   = (const float*)d_in[8];
  const float* emub  = (const float*)d_in[9];
  const float* epw   = (const float*)d_in[10];
  const float* epsb  = (const float*)d_in[11];
  const float* cw    = (const float*)d_in[12];
  const float* cb    = (const float*)d_in[13];
  const float* muw   = (const float*)d_in[14];
  const float* mub   = (const float*)d_in[15];
  const float* sgw   = (const float*)d_in[16];
  const float* sgwb  = (const float*)d_in[17];
  float* out = (float*)d_out;

  char* w = (char*)d_ws;
  auto alloc = [&](size_t bytes) { char* p = w; w += (bytes + 255) & ~(size_t)255; return p; };
  u16* Aw       = (u16*)alloc(4ull * 512 * 1024 * 2);
  u16* musgw16  = (u16*)alloc(4ull * 384 * 1216 * 2);
  u16* wih16    = (u16*)alloc(3072ull * 512 * 2);
  u64* hfA      = (u64*)alloc(65536);
  u64* hfB      = (u64*)alloc(65536);
  u32* flags    = (u32*)alloc(12288);          // team flags [0..2047], done [2048..]
  float* catb   = (float*)alloc(1536 * 4);
  float* hTt    = (float*)alloc(131072);
  float* hTn    = (float*)alloc(131072);
  float* Am     = (float*)alloc(32 * 192 * 4);
  float* Asg    = (float*)alloc(32 * 192 * 4);
  float* Sm     = (float*)alloc(1024);
  float* Ssg    = (float*)alloc(1024);
  float* smp    = (float*)alloc(32ull * 512 * 192 * 4);
  u16* hcB      = (u16*)alloc(32ull * 512 * 1216 * 2);   // also hosts wblob early
  char* un1     = alloc(32ull * 512 * 1216 * 4);          // xw then hbuf
  u16* xw       = (u16*)un1;
  float* hbuf   = (float*)un1;
  char* un2     = alloc(32ull * 1216 * 512 * 2);          // xT2 then hbT
  u16* xT2      = (u16*)un2;
  u16* hbT      = (u16*)un2;
  u16* wblob    = hcB;   // 6.3MB, consumed by k_gru before hcB is first written
  u32* done     = flags + 2048;

  if ((size_t)(w - (char*)d_ws) > ws_size) return;

  hipMemsetAsync(hfA, 0, 65536, stream);
  hipMemsetAsync(hfB, 0, 65536, stream);
  hipMemsetAsync(flags, 0, 12288, stream);

  // weight casts / reorders
  k_cast<<<dim3((3072 * 512 + 255) / 256), 256, 0, stream>>>(wih, wih16, 3072 * 512);
  k_musgw<<<dim3((4 * 384 * 1216 + 255) / 256), 256, 0, stream>>>(muw, sgw, musgw16, 4 * 384 * 1216);
  k_catb<<<dim3(6), 256, 0, stream>>>(mub, sgwb, catb);
  k_convw<<<dim3((4 * 512 * 1024 + 255) / 256), 256, 0, stream>>>(cw, Aw, 4 * 512 * 1024);
  k_gruw<<<dim3(1536), 256, 0, stream>>>(whh, wblob);
  k_txe<<<dim3(11, 16, 32), 256, 0, stream>>>(x_enc, xT2);

  // FUSED: GRU scan (64 WGs) + xw GEMM producers (2016 WGs)
  k_gru<<<dim3(2080), 256, 0, stream>>>(xT2, wih16, bih, xw, done,
                                        wblob, bhh, hfA, hfB, hTt, hTn, flags);

  // encoder head
  k_encsmall<<<dim3(6), 256, 0, stream>>>(hTt, emw, epw, Am, Asg, Sm, Ssg);
  k_build<<<dim3(512, 32), 256, 0, stream>>>(hTn, fw, fb, Am, Asg, Sm, Ssg, emub, epsb, eps, hbuf, smp);

  // flow layers (GEMMs use XCD-locality 1D swizzled grids: conv TPZ=40/NX=10, musg TPZ=12/NX=3)
  for (int l = 0; l < 4; ++l) {
    k_hbt<<<dim3(19, 16, 32), 256, 0, stream>>>(hbuf, hbT);
    gemm_bt<2, 40, 10><<<dim3(1280), 256, 0, stream>>>(Aw + (long)l * 512 * 1024, hbT, hcB, cb + l * 512,
        512, 1215, 1024, 1024, 512, 1216, 0, 1216 * 512, 512 * 1216, 511, 1214, 1215,
        hbuf, 512 * 1216, nullptr, 0);
    gemm_bt<5, 12, 3><<<dim3(384), 256, 0, stream>>>(hcB, musgw16 + (long)l * 384 * 1216, nullptr, catb + l * 384,
        512, 384, 1216, 1216, 1216, 384, 512 * 1216, 0, 0, 511, 383, 384,
        hbuf, 512 * 1216, smp, 512 * 192);
  }

  // out = transpose(sample)
  k_out<<<dim3(6, 16, 32), 256, 0, stream>>>(smp, out);
}

// Round 16
// 2062.033 us; speedup vs baseline: 1.0598x; 1.0598x over previous
//
#include <hip/hip_runtime.h>

using u16 = unsigned short;
using u32 = unsigned int;
using u64 = unsigned long long;
using f32x4 = __attribute__((ext_vector_type(4))) float;
using s16x8 = __attribute__((ext_vector_type(8))) short;
using u32x4 = __attribute__((ext_vector_type(4))) unsigned int;

// ---------- helpers ----------
__device__ __forceinline__ u16 f2b(float f) {
  union { float f; u32 u; } v; v.f = f;
  u32 r = v.u + 0x7fffu + ((v.u >> 16) & 1u);
  return (u16)(r >> 16);
}
__device__ __forceinline__ float b2f(u16 h) {
  union { u32 u; float f; } v; v.u = ((u32)h) << 16; return v.f;
}
__device__ __forceinline__ void gl_lds16(const u16* g, u16* l) {
  __builtin_amdgcn_global_load_lds(
      (const __attribute__((address_space(1))) void*)g,
      (__attribute__((address_space(3))) void*)l, 16, 0, 0);
}
// fast saturation-safe sigmoid / tanh (v_exp_f32-based)
__device__ __forceinline__ float fsigm(float x) {
  return 1.f / (1.f + __expf(-x));
}
__device__ __forceinline__ float ftanh(float x) {
  float ax = fabsf(x);
  float e2 = __expf(2.f * ax);
  float th = 1.f - 2.f / (e2 + 1.f);
  return copysignf(th, x);
}

// ---------- tiny prep kernels ----------
__global__ void k_cast(const float* __restrict__ s, u16* __restrict__ d, int n) {
  int i = blockIdx.x * 256 + threadIdx.x;
  if (i < n) d[i] = f2b(s[i]);
}

// INTERLEAVED mu|sg weight concat+cast: dst[l][r][k], r = 2p + s (s=0:mu, s=1:sg)
__global__ void k_musgw(const float* __restrict__ muw, const float* __restrict__ sgw,
                        u16* __restrict__ dst, int n) {
  int i = blockIdx.x * 256 + threadIdx.x;
  if (i >= n) return;
  int l = i / (384 * 1216);
  int r = (i / 1216) % 384;
  int k = i % 1216;
  int p = r >> 1;
  const float* s = (r & 1) ? (sgw + ((long)l * 192 + p) * 1216 + k)
                           : (muw + ((long)l * 192 + p) * 1216 + k);
  dst[i] = f2b(*s);
}

// interleaved bias
__global__ void k_catb(const float* __restrict__ mub, const float* __restrict__ sgb,
                       float* __restrict__ catb) {
  int i = blockIdx.x * 256 + threadIdx.x;
  if (i >= 1536) return;
  int l = i / 384, r = i % 384;
  int p = r >> 1;
  catb[i] = (r & 1) ? sgb[l * 192 + p] : mub[l * 192 + p];
}

// conv_w (NF,C,C,2) -> Aw[l][o][tap*512+i] bf16
__global__ void k_convw(const float* __restrict__ cw, u16* __restrict__ Aw, int n) {
  int i = blockIdx.x * 256 + threadIdx.x;
  if (i >= n) return;
  int l = i >> 19;
  int r1 = i & 524287;
  int o = r1 >> 10;
  int r2 = r1 & 1023;
  int tap = r2 >> 9;
  int ii = r2 & 511;
  Aw[i] = f2b(cw[(((long)(l * 512 + o)) * 512 + ii) * 2 + tap]);
}

// whh (3H,H) f32 -> fragment-ordered bf16 blob for k_gru (32 j-owners x 4 waves)
__global__ void k_gruw(const float* __restrict__ whh, u16* __restrict__ blob) {
  int i = blockIdx.x * 256 + threadIdx.x;   // 393216 threads
  int lane = i & 63;
  int c = (i >> 6) & 15;
  int g = (i >> 10) % 3;
  int wwv = i / 3072;
  int wv = wwv & 3, wg = wwv >> 2;
  int jbw = wv & 1, kw = wv >> 1;
  int j = wg * 32 + jbw * 16 + (lane & 15);
  int k = kw * 512 + c * 32 + (lane >> 4) * 8;
  const float* src = whh + ((long)(g * 1024 + j)) * 1024 + k;
  u16* dst = blob + (long)i * 8;
#pragma unroll
  for (int v = 0; v < 8; ++v) dst[v] = f2b(src[v]);
}

// x_enc (B,C,L) f32 -> xT (B*L, C) bf16
__global__ __launch_bounds__(256) void k_txe(const float* __restrict__ x, u16* __restrict__ xT) {
  __shared__ float tile[32][33];
  int l0 = blockIdx.x * 32, c0 = blockIdx.y * 32, b = blockIdx.z;
  int tid = threadIdx.x;
  for (int q = 0; q < 4; ++q) {
    int idx = tid + q * 256;
    int r = idx >> 5, cc = idx & 31;
    int l = l0 + cc;
    tile[r][cc] = (l < 336) ? x[((long)b * 512 + c0 + r) * 336 + l] : 0.f;
  }
  __syncthreads();
  for (int q = 0; q < 4; ++q) {
    int idx = tid + q * 256;
    int r = idx >> 5, cc = idx & 31;
    int l = l0 + r;
    if (l < 336) xT[((long)b * 336 + l) * 512 + c0 + cc] = f2b(tile[cc][r]);
  }
}

// hbuf (B,C,1216) f32 -> hbT (B,1216,C) bf16  — vectorized (float4 in, ushort4 out)
__global__ __launch_bounds__(256) void k_hbt(const float* __restrict__ hbuf, u16* __restrict__ hbT) {
  __shared__ float tile[32][65];
  int t0 = blockIdx.x * 64, c0 = blockIdx.y * 32, b = blockIdx.z;
  int tid = threadIdx.x;
#pragma unroll
  for (int q = 0; q < 2; ++q) {
    int idx = tid + q * 256;
    int r = idx >> 4, col = (idx & 15) * 4;
    *(float4*)&tile[r][col] =
        *(const float4*)&hbuf[((long)b * 512 + c0 + r) * 1216 + t0 + col];
  }
  __syncthreads();
#pragma unroll
  for (int q = 0; q < 2; ++q) {
    int idx = tid + q * 256;
    int t = idx >> 3, cg = (idx & 7) * 4;
    ushort4 o;
    o.x = f2b(tile[cg + 0][t]);
    o.y = f2b(tile[cg + 1][t]);
    o.z = f2b(tile[cg + 2][t]);
    o.w = f2b(tile[cg + 3][t]);
    *(ushort4*)&hbT[((long)b * 1216 + t0 + t) * 512 + c0 + cg] = o;
  }
}

// sample (B,C,P) f32 -> out (B,P,C) f32
__global__ __launch_bounds__(256) void k_out(const float* __restrict__ smp, float* __restrict__ out) {
  __shared__ float tile[32][33];
  int p0 = blockIdx.x * 32, c0 = blockIdx.y * 32, b = blockIdx.z;
  int tid = threadIdx.x;
  for (int q = 0; q < 4; ++q) {
    int idx = tid + q * 256;
    int r = idx >> 5, cc = idx & 31;
    tile[r][cc] = smp[((long)b * 512 + c0 + r) * 192 + p0 + cc];
  }
  __syncthreads();
  for (int q = 0; q < 4; ++q) {
    int idx = tid + q * 256;
    int r = idx >> 5, cc = idx & 31;
    out[((long)b * 192 + p0 + r) * 512 + c0 + cc] = tile[cc][r];
  }
}

// ---------- MFMA GEMM: C[M,N] = A(M,K) @ Bt(N,K)^T ----------
// MODE 0: bf16 out, +bias[n]
// MODE 2: conv: relu(+bias[m]), re-pad shift write to hc bf16, hbuf += 0.1*hc (t<1024)
// MODE 4: bf16 out, +bias[n], row-permuted m=b*336+t -> t*32+b (xw for GRU)
// MODE 5: interleaved mu|sg epilogue: n=2p+s; lane pair (mu,sg) via shfl_xor(1);
//         sample = mu + exp(0.5*sg)*sample*0.1 ; hbuf[..,1024+p] += 0.1*sample
// TPZ>0: XCD-locality swizzle (T1). 1D grid; bid = ((zhi*TPZ + tile)<<3)|xcd,
//        z = zhi*8+xcd -> all TPZ tiles of one z land on ONE XCD.
template<int MODE, int TPZ = 0, int NX = 1>
__global__ __launch_bounds__(256, 2)
void gemm_bt(const u16* __restrict__ A, const u16* __restrict__ Bt,
             void* __restrict__ Cv, const float* __restrict__ bias,
             int M, int N, int K, int lda, int ldb, int ldc,
             long sA, long sB, long sC,
             int arowmax, int browmax, int NT,
             float* __restrict__ hbufp, long sH,
             float* __restrict__ sampleP, long sS)
{
  __shared__ u16 As[128 * 64];
  __shared__ u16 Bs[128 * 64];
  const int tid = threadIdx.x;
  const int lane = tid & 63;
  const int wv = tid >> 6;
  int bx, by, bz;
  if (TPZ > 0) {
    int bid = (int)blockIdx.x;
    int xcd = bid & 7, idx = bid >> 3;
    int zhi = idx / TPZ, r = idx - zhi * TPZ;
    bz = zhi * 8 + xcd;
    by = r / NX;
    bx = r - by * NX;
  } else {
    bx = (int)blockIdx.x; by = (int)blockIdx.y; bz = (int)blockIdx.z;
  }
  const int z = bz;
  const u16* Ab = A + (long)z * sA;
  const u16* Bb = Bt + (long)z * sB;
  const int m0 = by * 128, n0 = bx * 128;
  const int wm = (wv >> 1) * 64, wn = (wv & 1) * 64;

  f32x4 acc[4][4] = {};

  for (int kt = 0; kt < K; kt += 64) {
#pragma unroll
    for (int s = 0; s < 4; ++s) {
      int row = (wv * 4 + s) * 8 + (lane >> 3);
      int ck = (lane & 7) ^ (row & 7);       // source chunk pre-swizzle (T2)
      int ra = m0 + row; if (ra > arowmax) ra = arowmax;
      gl_lds16(Ab + (long)ra * lda + (kt + ck * 8), As + (wv * 4 + s) * 512);
      int rb = n0 + row; if (rb > browmax) rb = browmax;
      gl_lds16(Bb + (long)rb * ldb + (kt + ck * 8), Bs + (wv * 4 + s) * 512);
    }
    __syncthreads();
#pragma unroll
    for (int kk = 0; kk < 64; kk += 32) {
      s16x8 af[4], bfr[4];
#pragma unroll
      for (int i = 0; i < 4; ++i) {
        int rowa = wm + i * 16 + (lane & 15);
        int offa = (rowa * 128 + (kk + 8 * (lane >> 4)) * 2) ^ ((rowa & 7) << 4);
        af[i] = *(const s16x8*)((const char*)As + offa);
        int rowb = wn + i * 16 + (lane & 15);
        int offb = (rowb * 128 + (kk + 8 * (lane >> 4)) * 2) ^ ((rowb & 7) << 4);
        bfr[i] = *(const s16x8*)((const char*)Bs + offb);
      }
#pragma unroll
      for (int i = 0; i < 4; ++i)
#pragma unroll
        for (int j = 0; j < 4; ++j)
          acc[i][j] = __builtin_amdgcn_mfma_f32_16x16x32_bf16(af[i], bfr[j], acc[i][j], 0, 0, 0);
    }
    __syncthreads();
  }

  u16* Cb16 = (u16*)Cv;
#pragma unroll
  for (int i = 0; i < 4; ++i) {
#pragma unroll
    for (int j = 0; j < 4; ++j) {
      const int mb = m0 + wm + i * 16 + 4 * (lane >> 4);
      const int n = n0 + wn + j * 16 + (lane & 15);
      if (n >= NT) continue;
      f32x4 v = acc[i][j];
      if (MODE == 0) {
        float bn = bias[n];
        u16* Cp = Cb16;
#pragma unroll
        for (int r = 0; r < 4; ++r)
          Cp[(long)(mb + r) * ldc + n] = f2b(v[r] + bn);
      } else if (MODE == 4) {
        float bn = bias[n];
        u16* Cp = Cb16;
#pragma unroll
        for (int r = 0; r < 4; ++r) {
          int m = mb + r;
          int bb = m / 336;
          int tt = m - bb * 336;
          Cp[(long)(tt * 32 + bb) * ldc + n] = f2b(v[r] + bn);
        }
      } else if (MODE == 2) {
        u16* Cp = Cb16 + (long)z * sC;
        float* hb = hbufp + (long)z * sH;
#pragma unroll
        for (int r = 0; r < 4; ++r) {
          int m = mb + r;
          float x = v[r] + bias[m];
          x = fmaxf(x, 0.0f);
          u16 hx = f2b(x);
          Cp[(long)m * ldc + (n + 1)] = hx;
          if (n + 1 < 1024) hb[(long)m * 1216 + (n + 1)] += 0.1f * x;
          if (n == 0) { Cp[(long)m * ldc] = hx; hb[(long)m * 1216] += 0.1f * x; }
        }
      } else { // MODE 5
        float bn = bias[n];
        float* hb = hbufp + (long)z * sH;
        float* smp = sampleP + (long)z * sS;
        const int p = n >> 1;
#pragma unroll
        for (int r = 0; r < 4; ++r) {
          float val = v[r] + bn;              // even lane: mu ; odd lane: sg
          float other = __shfl_xor(val, 1);   // partner value
          if ((lane & 1) == 0) {
            int m = mb + r;
            long si = (long)m * 192 + p;
            float snew = val + __expf(0.5f * other) * smp[si] * 0.1f;
            smp[si] = snew;
            hb[(long)m * 1216 + 1024 + p] += 0.1f * snew;
          }
        }
      }
    }
  }
}

// ---------- GRU scan: TWO parallel 32-WG teams (batch halves), wide-sc1 transport ----------
// 64 WGs: team q = wg>>5 owns batch half b in [q*16, q*16+16); tw = wg&31 owns j-range.
// Producer order: h stores(sc1,16B) -> s_waitcnt vmcnt(0) -> syncthreads -> flag store.
// Consumer order: wave0 polls own team's 32 flags -> syncthreads -> h loads(sc1) -> vmcnt(0).
__global__ __launch_bounds__(256, 1)
void k_gru(const u16* __restrict__ xw, const u16* __restrict__ wblob,
           const float* __restrict__ bhh, u64* __restrict__ hfA, u64* __restrict__ hfB,
           float* __restrict__ hTt, float* __restrict__ hTn, u32* __restrict__ flags)
{
  __shared__ float part[6][32][32];   // [kw*3+g][j_local][(16q+s4)^swz]  24KB
  const int tid = threadIdx.x;
  const int lane = tid & 63;
  const int wv = tid >> 6;
  const int q = (int)(blockIdx.x >> 5);   // team = batch half
  const int tw = (int)(blockIdx.x & 31);  // j-range owner within team
  const int jbw = wv & 1, kw = wv >> 1;
  u32* __restrict__ myflags = flags + q * 1024;

  // persistent weights: bfr[g][c] covers j = tw*32+jbw*16+(lane&15), k = kw*512+c*32+(lane>>4)*8..+7
  s16x8 bfr[3][16];
  {
    const u16* wp = wblob + (long)(tw * 4 + wv) * 24576 + lane * 8;
#pragma unroll
    for (int g = 0; g < 3; ++g)
#pragma unroll
      for (int c = 0; c < 16; ++c)
        bfr[g][c] = *(const s16x8*)(wp + (g * 16 + c) * 512);
  }

  // gate-phase thread map (tid<128): bq16 = b within team, jg -> 4 j values
  const int bq16 = tid & 15, jg = (tid >> 4) & 7;
  const int j0 = tw * 32 + jg * 4;
  const int bb = q * 16 + bq16;           // global batch index
  float b3[3][4];
#pragma unroll
  for (int g = 0; g < 3; ++g)
#pragma unroll
    for (int jj = 0; jj < 4; ++jj) b3[g][jj] = bhh[g * 1024 + j0 + jj];
  ushort4 hold = make_ushort4(0, 0, 0, 0);

  // producer 16B store base (even-jg threads; covers w=0,1 = jg,jg+1 quads)
  const long hoff64 = (long)(tw * 2 + q) * 128 + ((long)(jg >> 1) * 16 + bq16) * 2;
  const int myflag = tw * 32;

  for (int t = 0; t < 336; ++t) {
    const u64* __restrict__ hr = (t & 1) ? hfB : hfA;
    u64* __restrict__ hw = (t & 1) ? hfA : hfB;

    // prefetch xw slice (gate threads only)
    ushort4 xr = {}, xz = {}, xn = {};
    if (tid < 128) {
      const u16* xp = xw + ((long)t * 32 + bb) * 3072 + j0;
      xr = *(const ushort4*)(xp);
      xz = *(const ushort4*)(xp + 1024);
      xn = *(const ushort4*)(xp + 2048);
    }

    // flag poll: wave 0 only, one flag per lane (own team)
    if (t > 0) {
      if (wv == 0) {
        const int fi = (lane & 31) * 32;
        int spins = 0;
        while (true) {
          u32 v = __hip_atomic_load(&myflags[fi], __ATOMIC_RELAXED, __HIP_MEMORY_SCOPE_AGENT);
          if (__ballot(v >= (u32)t) == ~0ull) break;
          __builtin_amdgcn_s_sleep(1);
          if (++spins > (1 << 22)) break;   // safety
        }
      }
    }
    __syncthreads();     // release waves; also WAR guard on part[]
    __builtin_amdgcn_sched_barrier(0);

    // consume h_t (own batch half): 16 x 16B sc1 loads, all in flight, one wait
    u32x4 md[16];
#pragma unroll
    for (int c = 0; c < 16; ++c) {
      const int cg = kw * 16 + c;
      u64 a0 = (u64)(const void*)(hr + ((long)(cg * 2 + q) * 64 + lane) * 2);
      asm volatile("global_load_dwordx4 %0, %1, off sc1" : "=v"(md[c]) : "v"(a0) : "memory");
    }
    asm volatile("s_waitcnt vmcnt(0)" ::: "memory");
    __builtin_amdgcn_sched_barrier(0);   // rule #18: MFMA must not hoist above waitcnt

    f32x4 acc[3] = {};
#pragma unroll
    for (int c = 0; c < 16; ++c) {
      union { u32x4 d; s16x8 v; } au;
      au.d = md[c];
#pragma unroll
      for (int g = 0; g < 3; ++g)
        acc[g] = __builtin_amdgcn_mfma_f32_16x16x32_bf16(au.v, bfr[g][c], acc[g], 0, 0, 0);
    }
    // write partials (b128, XOR-swizzled slots; p=q half only)
    {
      const int jl = jbw * 16 + (lane & 15);
      const int swz = ((jl & 1) << 4) | ((jl & 6) << 1);
      const int s4 = (lane >> 4) * 4;
#pragma unroll
      for (int g = 0; g < 3; ++g)
        *(f32x4*)&part[kw * 3 + g][jl][(16 * q + s4) ^ swz] = acc[g];
    }
    __syncthreads();

    // gates: 128 threads x 4 values (fast exp)
    if (tid < 128) {
      float hnew[4];
#pragma unroll
      for (int jj = 0; jj < 4; ++jj) {
        const int jl = jg * 4 + jj;
        const int swz = ((jl & 1) << 4) | ((jl & 6) << 1);
        const int slot = (16 * q + bq16) ^ swz;
        float s0 = part[0][jl][slot] + part[3][jl][slot] + b3[0][jj];
        float s1 = part[1][jl][slot] + part[4][jl][slot] + b3[1][jj];
        float s2 = part[2][jl][slot] + part[5][jl][slot] + b3[2][jj];
        float xrv = b2f(((const u16*)&xr)[jj]);
        float xzv = b2f(((const u16*)&xz)[jj]);
        float xnv = b2f(((const u16*)&xn)[jj]);
        float rg = fsigm(xrv + s0);
        float zg = fsigm(xzv + s1);
        float ng = ftanh(xnv + rg * s2);
        float holdv = b2f(((const u16*)&hold)[jj]);
        hnew[jj] = (1.f - zg) * ng + zg * holdv;
      }
      ((u16*)&hold)[0] = f2b(hnew[0]);
      ((u16*)&hold)[1] = f2b(hnew[1]);
      ((u16*)&hold)[2] = f2b(hnew[2]);
      ((u16*)&hold)[3] = f2b(hnew[3]);

      // publish: pair (jg, jg^1) via shfl_xor(16); even-jg lanes store 16B sc1
      {
        union { ushort4 s; u32 d[2]; } hq; hq.s = hold;
        u32 p0 = (u32)__shfl_xor((int)hq.d[0], 16);
        u32 p1 = (u32)__shfl_xor((int)hq.d[1], 16);
        if ((lane & 16) == 0) {   // even jg
          union { u32 d[4]; u32x4 v; } st;
          st.d[0] = hq.d[0]; st.d[1] = hq.d[1]; st.d[2] = p0; st.d[3] = p1;
          u64 ad = (u64)(void*)(hw + hoff64);
          asm volatile("global_store_dwordx4 %0, %1, off sc1" :: "v"(ad), "v"(st.v) : "memory");
        }
      }
      if (t == 335) {
#pragma unroll
        for (int jj = 0; jj < 4; ++jj) hTt[(j0 + jj) * 32 + bb] = hnew[jj];
        *(float4*)(hTn + bb * 1024 + j0) = make_float4(hnew[0], hnew[1], hnew[2], hnew[3]);
      }
    }
    asm volatile("s_waitcnt vmcnt(0)" ::: "memory");  // h store acked at coherence point
    __syncthreads();                                   // all waves' stores drained
    if (tid == 0)
      __hip_atomic_store(&myflags[myflag], (u32)(t + 1), __ATOMIC_RELAXED, __HIP_MEMORY_SCOPE_AGENT);
  }
}

// ---------- encoder-head micro GEMMs ----------
__global__ __launch_bounds__(256) void k_encsmall(
    const float* __restrict__ hTt, const float* __restrict__ emw, const float* __restrict__ epw,
    float* __restrict__ Am, float* __restrict__ Asg, float* __restrict__ Sm, float* __restrict__ Ssg)
{
  int q = blockIdx.x * 256 + threadIdx.x;
  int p = q >> 3, bg = q & 7;
  float am[4] = {0.f, 0.f, 0.f, 0.f}, as[4] = {0.f, 0.f, 0.f, 0.f};
  float sm = 0.f, ss = 0.f;
  const float* wmp = emw + (long)p * 1024;
  const float* wsp = epw + (long)p * 1024;
  for (int k = 0; k < 1024; ++k) {
    float a = wmp[k], b = wsp[k];
    f32x4 hv = *(const f32x4*)(hTt + k * 32 + bg * 4);
#pragma unroll
    for (int i = 0; i < 4; ++i) { am[i] += a * hv[i]; as[i] += b * hv[i]; }
    sm += a; ss += b;
  }
#pragma unroll
  for (int i = 0; i < 4; ++i) {
    Am[(bg * 4 + i) * 192 + p] = am[i];
    Asg[(bg * 4 + i) * 192 + p] = as[i];
  }
  if (bg == 0) { Sm[p] = sm; Ssg[p] = ss; }
}

// ---------- build hbuf (enc | sample) + sample ----------
__global__ __launch_bounds__(256) void k_build(
    const float* __restrict__ hTn, const float* __restrict__ fw, const float* __restrict__ fb,
    const float* __restrict__ Am, const float* __restrict__ Asg,
    const float* __restrict__ Sm, const float* __restrict__ Ssg,
    const float* __restrict__ emub, const float* __restrict__ epsb,
    const float* __restrict__ eps, float* __restrict__ hbuf, float* __restrict__ sample)
{
  int c = blockIdx.x, b = blockIdx.y, tid = threadIdx.x;
  float fwc = fw[c], fbc = fb[c];
  long hb0 = ((long)b * 512 + c) * 1216;
  const float* hrow = hTn + b * 1024;
  for (int q = 0; q < 4; ++q) {
    int tt = tid + q * 256;
    hbuf[hb0 + tt] = hrow[tt] * fwc + fbc;
  }
  if (tid < 192) {
    int p = tid;
    float mu_e = fwc * Am[b * 192 + p] + fbc * Sm[p] + emub[p];
    float pse = fwc * Asg[b * 192 + p] + fbc * Ssg[p] + epsb[p];
    float sgv = (pse > 15.f) ? pse : log1pf(__expf(pse));
    long si = ((long)b * 512 + c) * 192 + p;
    float smp = mu_e + __expf(0.5f * sgv) * eps[si];
    sample[si] = smp;
    hbuf[hb0 + 1024 + p] = smp;
  }
}

// ---------- launch ----------
extern "C" void kernel_launch(void* const* d_in, const int* in_sizes, int n_in,
                              void* d_out, int out_size, void* d_ws, size_t ws_size,
                              hipStream_t stream)
{
  const float* x_enc = (const float*)d_in[0];
  const float* eps   = (const float*)d_in[1];
  const float* wih   = (const float*)d_in[2];
  const float* whh   = (const float*)d_in[3];
  const float* bih   = (const float*)d_in[4];
  const float* bhh   = (const float*)d_in[5];
  const float* fw    = (const float*)d_in[6];
  const float* fb    = (const float*)d_in[7];
  const float* emw   = (const float*)d_in[8];
  const float* emub  = (const float*)d_in[9];
  const float* epw   = (const float*)d_in[10];
  const float* epsb  = (const float*)d_in[11];
  const float* cw    = (const float*)d_in[12];
  const float* cb    = (const float*)d_in[13];
  const float* muw   = (const float*)d_in[14];
  const float* mub   = (const float*)d_in[15];
  const float* sgw   = (const float*)d_in[16];
  const float* sgwb  = (const float*)d_in[17];
  float* out = (float*)d_out;

  char* w = (char*)d_ws;
  auto alloc = [&](size_t bytes) { char* p = w; w += (bytes + 255) & ~(size_t)255; return p; };
  u16* Aw       = (u16*)alloc(4ull * 512 * 1024 * 2);
  u16* musgw16  = (u16*)alloc(4ull * 384 * 1216 * 2);
  u16* wih16    = (u16*)alloc(3072ull * 512 * 2);
  u64* hfA      = (u64*)alloc(65536);
  u64* hfB      = (u64*)alloc(65536);
  u32* flags    = (u32*)alloc(8192);
  float* catb   = (float*)alloc(1536 * 4);
  float* hTt    = (float*)alloc(131072);
  float* hTn    = (float*)alloc(131072);
  float* Am     = (float*)alloc(32 * 192 * 4);
  float* Asg    = (float*)alloc(32 * 192 * 4);
  float* Sm     = (float*)alloc(1024);
  float* Ssg    = (float*)alloc(1024);
  float* smp    = (float*)alloc(32ull * 512 * 192 * 4);
  u16* hcB      = (u16*)alloc(32ull * 512 * 1216 * 2);   // also hosts wblob early
  char* un1     = alloc(32ull * 512 * 1216 * 4);          // xw then hbuf
  u16* xw       = (u16*)un1;
  float* hbuf   = (float*)un1;
  char* un2     = alloc(32ull * 1216 * 512 * 2);          // xT then hbT
  u16* xT       = (u16*)un2;
  u16* hbT      = (u16*)un2;
  u16* wblob    = hcB;   // 6.3MB, consumed by k_gru before hcB is first written

  if ((size_t)(w - (char*)d_ws) > ws_size) return;

  hipMemsetAsync(hfA, 0, 65536, stream);
  hipMemsetAsync(hfB, 0, 65536, stream);
  hipMemsetAsync(flags, 0, 8192, stream);

  // weight casts / reorders
  k_cast<<<dim3((3072 * 512 + 255) / 256), 256, 0, stream>>>(wih, wih16, 3072 * 512);
  k_musgw<<<dim3((4 * 384 * 1216 + 255) / 256), 256, 0, stream>>>(muw, sgw, musgw16, 4 * 384 * 1216);
  k_catb<<<dim3(6), 256, 0, stream>>>(mub, sgwb, catb);
  k_convw<<<dim3((4 * 512 * 1024 + 255) / 256), 256, 0, stream>>>(cw, Aw, 4 * 512 * 1024);
  k_gruw<<<dim3(1536), 256, 0, stream>>>(whh, wblob);
  k_txe<<<dim3(11, 16, 32), 256, 0, stream>>>(x_enc, xT);

  // xw = x @ wih^T + bih, rows permuted to [t][b]
  gemm_bt<4><<<dim3(24, 84, 1), 256, 0, stream>>>(xT, wih16, xw, bih,
      10752, 3072, 512, 512, 512, 3072, 0, 0, 0, 10751, 3071, 3072,
      nullptr, 0, nullptr, 0);

  // GRU scan: two parallel 32-WG teams (batch halves)
  k_gru<<<dim3(64), 256, 0, stream>>>(xw, wblob, bhh, hfA, hfB, hTt, hTn, flags);

  // encoder head
  k_encsmall<<<dim3(6), 256, 0, stream>>>(hTt, emw, epw, Am, Asg, Sm, Ssg);
  k_build<<<dim3(512, 32), 256, 0, stream>>>(hTn, fw, fb, Am, Asg, Sm, Ssg, emub, epsb, eps, hbuf, smp);

  // flow layers (GEMMs use XCD-locality 1D swizzled grids: conv TPZ=40/NX=10, musg TPZ=12/NX=3)
  for (int l = 0; l < 4; ++l) {
    k_hbt<<<dim3(19, 16, 32), 256, 0, stream>>>(hbuf, hbT);
    gemm_bt<2, 40, 10><<<dim3(1280), 256, 0, stream>>>(Aw + (long)l * 512 * 1024, hbT, hcB, cb + l * 512,
        512, 1215, 1024, 1024, 512, 1216, 0, 1216 * 512, 512 * 1216, 511, 1214, 1215,
        hbuf, 512 * 1216, nullptr, 0);
    gemm_bt<5, 12, 3><<<dim3(384), 256, 0, stream>>>(hcB, musgw16 + (long)l * 384 * 1216, nullptr, catb + l * 384,
        512, 384, 1216, 1216, 1216, 384, 512 * 1216, 0, 0, 511, 383, 384,
        hbuf, 512 * 1216, smp, 512 * 192);
  }

  // out = transpose(sample)
  k_out<<<dim3(6, 16, 32), 256, 0, stream>>>(smp, out);
}